// Round 4
// baseline (210.058 us; speedup 1.0000x reference)
//
#include <hip/hip_runtime.h>
#include <hip/hip_bf16.h>

#define Bb 2
#define Nn 32
#define Tt 32
#define Mm 256
#define Ll 20
#define Hh 128
#define Dd 128
#define TAUu 64
#define RSQRT_D 0.08838834764831843f

__device__ __forceinline__ float rlane(float v, int l) {
    return __int_as_float(__builtin_amdgcn_readlane(__float_as_int(v), l));
}

// ================= Kernel 1: polyline/map encoder =================
// grid 512, block 128 (2 waves). thread = output unit h. Layer-1 values live
// in lanes; layer-2 matvec via v_readlane (VALU) + per-lane vector weight
// loads. Polyline coords and weights stream through SMEM (uniform s_load).
__global__ __launch_bounds__(128) void k_map(
    const float* __restrict__ poly, const float* __restrict__ pmask,
    const int* __restrict__ ptype, const int* __restrict__ ptl, const int* __restrict__ proute,
    const float* __restrict__ pm_w1, const float* __restrict__ pm_b1,
    const float* __restrict__ pm_w2, const float* __restrict__ pm_b2,
    const float* __restrict__ type_emb, const float* __restrict__ tl_emb, const float* __restrict__ route_emb,
    const float* __restrict__ mo_w1, const float* __restrict__ mo_b1,
    const float* __restrict__ mo_w2, const float* __restrict__ mo_b2,
    float* __restrict__ map_node, float* __restrict__ map_nodeT, float* __restrict__ map_center)
{
    int bm = blockIdx.x;
    int b  = bm >> 8, m = bm & 255;
    int h  = threadIdx.x;
    int lam = h & 63, wv = h >> 6;
    int obase = ((wv ^ 1) << 6) + lam;
    __shared__ float xch[Ll][Hh];

    const float* pp = poly + bm * (Ll*2);
    float w1x = pm_w1[h], w1y = pm_w1[Hh+h], b1v = pm_b1[h];
    float h1r[Ll];
    #pragma unroll
    for (int l = 0; l < Ll; ++l) {
        float xl = pp[2*l], yl = pp[2*l+1];            // uniform -> s_load
        h1r[l] = fmaxf(fmaf(w1x, xl, fmaf(w1y, yl, b1v)), 0.f);
    }
    #pragma unroll
    for (int l = 0; l < Ll; ++l) xch[l][h] = h1r[l];
    __syncthreads();
    float lo[Ll], hi[Ll];
    #pragma unroll
    for (int l = 0; l < Ll; ++l) {
        float o = xch[l][obase];
        lo[l] = wv ? o : h1r[l];
        hi[l] = wv ? h1r[l] : o;
    }
    float b2v = pm_b2[h];
    float acc[Ll];
    #pragma unroll
    for (int l = 0; l < Ll; ++l) acc[l] = b2v;
    #pragma unroll
    for (int k = 0; k < 64; ++k) {
        float w = pm_w2[k*Hh + h];
        #pragma unroll
        for (int l = 0; l < Ll; ++l) acc[l] = fmaf(rlane(lo[l], k), w, acc[l]);
    }
    #pragma unroll
    for (int k = 0; k < 64; ++k) {
        float w = pm_w2[(64+k)*Hh + h];
        #pragma unroll
        for (int l = 0; l < Ll; ++l) acc[l] = fmaf(rlane(hi[l], k), w, acc[l]);
    }
    float mx = 0.f;   // relu floor
    #pragma unroll
    for (int l = 0; l < Ll; ++l) mx = fmaxf(mx, acc[l]);

    int ti = min(max(ptype[bm], 0), 3);
    int si = min(max(ptl[bm], 0), 7);
    int ri = min(max(proute[bm], 0), 1);
    float hval = mx + type_emb[ti*Hh+h] + tl_emb[si*Hh+h] + route_emb[ri*Hh+h];

    // mo layer 1
    __syncthreads();
    xch[0][h] = hval;
    __syncthreads();
    {
        float o = xch[0][obase];
        float l1 = wv ? o : hval, h1 = wv ? hval : o;
        float a1 = mo_b1[h];
        #pragma unroll
        for (int k = 0; k < 64; ++k) a1 = fmaf(rlane(l1, k), mo_w1[k*Hh + h], a1);
        #pragma unroll
        for (int k = 0; k < 64; ++k) a1 = fmaf(rlane(h1, k), mo_w1[(64+k)*Hh + h], a1);
        hval = fmaxf(a1, 0.f);
    }
    // mo layer 2
    __syncthreads();
    xch[0][h] = hval;
    __syncthreads();
    float val;
    {
        float o = xch[0][obase];
        float l1 = wv ? o : hval, h1 = wv ? hval : o;
        float a2 = mo_b2[h];
        #pragma unroll
        for (int k = 0; k < 64; ++k) a2 = fmaf(rlane(l1, k), mo_w2[k*Dd + h], a2);
        #pragma unroll
        for (int k = 0; k < 64; ++k) a2 = fmaf(rlane(h1, k), mo_w2[(64+k)*Dd + h], a2);
        val = a2;
    }
    float mk = (pmask[bm] > 0.5f) ? 1.f : 0.f;
    val *= mk;
    map_node[bm*Dd + h] = val;
    map_nodeT[(b*Dd + h)*Mm + m] = val;
    if (h == 0) {
        float sx = 0.f, sy = 0.f;
        #pragma unroll
        for (int l = 0; l < Ll; ++l) { sx += pp[2*l]; sy += pp[2*l+1]; }
        map_center[bm*2+0] = sx / (float)Ll;
        map_center[bm*2+1] = sy / (float)Ll;
    }
}

// ================= Kernel 2: agent embedding =================
// grid 512, block 128, 4 rows/block. Same readlane matvec pattern.
__global__ __launch_bounds__(128) void k_agent(
    const float* __restrict__ astate, const float* __restrict__ amask,
    const float* __restrict__ ae_w1, const float* __restrict__ ae_b1,
    const float* __restrict__ ae_w2, const float* __restrict__ ae_b2,
    const float* __restrict__ ae_w3, const float* __restrict__ ae_b3,
    float* __restrict__ a_emb)
{
    int r0 = blockIdx.x * 4;
    int h  = threadIdx.x;
    int lam = h & 63, wv = h >> 6;
    int obase = ((wv ^ 1) << 6) + lam;
    __shared__ float xch[4][Hh];

    float w1[5];
    #pragma unroll
    for (int k = 0; k < 5; ++k) w1[k] = ae_w1[k*Hh + h];
    float b1v = ae_b1[h];
    float a1[4];
    #pragma unroll
    for (int r = 0; r < 4; ++r) {
        const float* st = astate + (r0+r)*5;     // uniform -> s_load
        float a = b1v;
        #pragma unroll
        for (int k = 0; k < 5; ++k) a = fmaf(w1[k], st[k], a);
        a1[r] = fmaxf(a, 0.f);
    }
    // layer 2
    #pragma unroll
    for (int r = 0; r < 4; ++r) xch[r][h] = a1[r];
    __syncthreads();
    float lo[4], hi[4];
    #pragma unroll
    for (int r = 0; r < 4; ++r) {
        float o = xch[r][obase];
        lo[r] = wv ? o : a1[r];
        hi[r] = wv ? a1[r] : o;
    }
    float b2v = ae_b2[h];
    float ac[4] = {b2v, b2v, b2v, b2v};
    #pragma unroll
    for (int k = 0; k < 64; ++k) {
        float w = ae_w2[k*Hh + h];
        #pragma unroll
        for (int r = 0; r < 4; ++r) ac[r] = fmaf(rlane(lo[r], k), w, ac[r]);
    }
    #pragma unroll
    for (int k = 0; k < 64; ++k) {
        float w = ae_w2[(64+k)*Hh + h];
        #pragma unroll
        for (int r = 0; r < 4; ++r) ac[r] = fmaf(rlane(hi[r], k), w, ac[r]);
    }
    #pragma unroll
    for (int r = 0; r < 4; ++r) a1[r] = fmaxf(ac[r], 0.f);
    // layer 3
    __syncthreads();
    #pragma unroll
    for (int r = 0; r < 4; ++r) xch[r][h] = a1[r];
    __syncthreads();
    #pragma unroll
    for (int r = 0; r < 4; ++r) {
        float o = xch[r][obase];
        lo[r] = wv ? o : a1[r];
        hi[r] = wv ? a1[r] : o;
    }
    float b3v = ae_b3[h];
    #pragma unroll
    for (int r = 0; r < 4; ++r) ac[r] = b3v;
    #pragma unroll
    for (int k = 0; k < 64; ++k) {
        float w = ae_w3[k*Dd + h];
        #pragma unroll
        for (int r = 0; r < 4; ++r) ac[r] = fmaf(rlane(lo[r], k), w, ac[r]);
    }
    #pragma unroll
    for (int k = 0; k < 64; ++k) {
        float w = ae_w3[(64+k)*Dd + h];
        #pragma unroll
        for (int r = 0; r < 4; ++r) ac[r] = fmaf(rlane(hi[r], k), w, ac[r]);
    }
    #pragma unroll
    for (int r = 0; r < 4; ++r) {
        float mk = (amask[r0+r] > 0.5f) ? 1.f : 0.f;
        a_emb[(r0+r)*Dd + h] = ac[r] * mk;
    }
}

// ================= Kernel 3: fused map-attention + neighbor + output =================
// grid 512, block 256 (4 waves), 4 rows/block (same b,n; t0..t0+3).
__global__ __launch_bounds__(256) void k_fused(
    const float* __restrict__ astate, const float* __restrict__ amask,
    const float* __restrict__ pmask,
    const float* __restrict__ a_emb, const float* __restrict__ map_node,
    const float* __restrict__ map_nodeT, const float* __restrict__ map_center,
    const float* __restrict__ mr_w1, const float* __restrict__ mr_b1,
    const float* __restrict__ mr_w2, const float* __restrict__ mr_b2,
    const float* __restrict__ nr_w1, const float* __restrict__ nr_b1,
    const float* __restrict__ nr_w2, const float* __restrict__ nr_b2,
    const float* __restrict__ to_w1, const float* __restrict__ to_b1,
    const float* __restrict__ to_w2, const float* __restrict__ to_b2,
    float* __restrict__ out)
{
    int r0 = blockIdx.x * 4;
    int b  = r0 >> 10;
    int i  = (r0 >> 5) & 31;
    int t0 = r0 & 31;
    int tid = threadIdx.x;
    int lam = tid & 63, wv = tid >> 6;

    __shared__ float tau[4][3*Dd];      // [a_emb | map_ctx | nbr_ctx]
    __shared__ float lg4[4][Mm];
    __shared__ float p4[Mm][4];
    __shared__ float ctxp[4][512];
    __shared__ float w1n_s[5*Hh];
    __shared__ float b1n_s[Hh];
    __shared__ float w2n_s[Hh];
    __shared__ float jd[4][Nn][5];
    __shared__ float lgn[4][Nn];
    __shared__ float p4n[Nn][4];
    __shared__ float g1s[4][Hh];

    // ---- setup ----
    for (int q = tid; q < 512; q += 256) tau[q>>7][q&127] = a_emb[(r0 + (q>>7))*Dd + (q&127)];
    for (int q = tid; q < 5*Hh; q += 256) w1n_s[q] = nr_w1[q];
    if (tid < Hh) { b1n_s[tid] = nr_b1[tid]; w2n_s[tid] = nr_w2[tid]; }
    if (tid < 128) {
        int rr = tid >> 5, j = tid & 31;
        int rj = (b*Nn + j)*Tt + t0 + rr;
        jd[rr][j][0] = astate[rj*5+0];
        jd[rr][j][1] = astate[rj*5+1];
        jd[rr][j][2] = astate[rj*5+3];
        jd[rr][j][3] = astate[rj*5+4];
        jd[rr][j][4] = amask[rj];
    }
    __syncthreads();

    // ---- Phase M-B: map logits (thread = m) ----
    {
        int m = tid;
        float cx = map_center[(b*Mm+m)*2+0];
        float cy = map_center[(b*Mm+m)*2+1];
        float rx[4], ry[4], dv[4], sA[4], dt[4];
        float b2c = mr_b2[0];
        #pragma unroll
        for (int r = 0; r < 4; ++r) {
            float px = astate[(r0+r)*5+0];       // uniform -> s_load
            float py = astate[(r0+r)*5+1];
            rx[r] = cx - px; ry[r] = cy - py;
            dv[r] = sqrtf(rx[r]*rx[r] + ry[r]*ry[r]);
            sA[r] = b2c; dt[r] = 0.f;
        }
        #pragma unroll 4
        for (int k = 0; k < Hh; ++k) {
            float wa = mr_w1[k], wb = mr_w1[Hh+k], wc = mr_w1[2*Hh+k];   // s_load
            float bb = mr_b1[k], w2 = mr_w2[k];
            #pragma unroll
            for (int r = 0; r < 4; ++r) {
                float t1 = fmaf(rx[r], wa, fmaf(ry[r], wb, fmaf(dv[r], wc, bb)));
                t1 = fmaxf(t1, 0.f);
                sA[r] = fmaf(t1, w2, sA[r]);
            }
        }
        #pragma unroll 4
        for (int d = 0; d < Dd; ++d) {
            float v = map_nodeT[(b*Dd + d)*Mm + m];   // vector, coalesced
            #pragma unroll
            for (int r = 0; r < 4; ++r)
                dt[r] = fmaf(v, a_emb[(r0+r)*Dd + d], dt[r]);   // uniform -> s_load
        }
        bool mk = pmask[b*Mm+m] > 0.5f;
        #pragma unroll
        for (int r = 0; r < 4; ++r)
            lg4[r][m] = mk ? fmaf(dt[r], RSQRT_D, sA[r]) : -1e30f;
    }
    __syncthreads();

    // ---- Phase M-C: softmax over 256 m, wave wv = row wv ----
    {
        float x0 = lg4[wv][lam], x1 = lg4[wv][64+lam], x2 = lg4[wv][128+lam], x3 = lg4[wv][192+lam];
        float mxv = fmaxf(fmaxf(x0,x1), fmaxf(x2,x3));
        for (int off = 32; off; off >>= 1) mxv = fmaxf(mxv, __shfl_xor(mxv, off));
        float e0 = (x0 > -1e29f) ? expf(x0-mxv) : 0.f;
        float e1 = (x1 > -1e29f) ? expf(x1-mxv) : 0.f;
        float e2 = (x2 > -1e29f) ? expf(x2-mxv) : 0.f;
        float e3 = (x3 > -1e29f) ? expf(x3-mxv) : 0.f;
        float sm = e0+e1+e2+e3;
        for (int off = 32; off; off >>= 1) sm += __shfl_xor(sm, off);
        float inv = 1.f / fmaxf(sm, 1e-9f);
        p4[lam][wv]     = e0*inv;
        p4[64+lam][wv]  = e1*inv;
        p4[128+lam][wv] = e2*inv;
        p4[192+lam][wv] = e3*inv;
    }
    __syncthreads();

    // ---- Phase M-D: map_ctx = p @ map_node ; wave wv handles m-chunk [64wv,64wv+64) ----
    {
        int m0 = wv * 64;
        float4 pv = *(const float4*)&p4[m0 + lam][0];
        float pr0 = pv.x, pr1 = pv.y, pr2 = pv.z, pr3 = pv.w;
        float a00=0.f,a01=0.f,a10=0.f,a11=0.f,a20=0.f,a21=0.f,a30=0.f,a31=0.f;
        #pragma unroll
        for (int mm = 0; mm < 64; ++mm) {
            const float* np = map_node + (b*Mm + m0 + mm)*Dd;
            float v0 = np[lam], v1 = np[64+lam];
            float s0 = rlane(pr0, mm), s1 = rlane(pr1, mm), s2 = rlane(pr2, mm), s3 = rlane(pr3, mm);
            a00 = fmaf(s0, v0, a00); a01 = fmaf(s0, v1, a01);
            a10 = fmaf(s1, v0, a10); a11 = fmaf(s1, v1, a11);
            a20 = fmaf(s2, v0, a20); a21 = fmaf(s2, v1, a21);
            a30 = fmaf(s3, v0, a30); a31 = fmaf(s3, v1, a31);
        }
        ctxp[wv][0*Dd + lam] = a00; ctxp[wv][0*Dd + 64+lam] = a01;
        ctxp[wv][1*Dd + lam] = a10; ctxp[wv][1*Dd + 64+lam] = a11;
        ctxp[wv][2*Dd + lam] = a20; ctxp[wv][2*Dd + 64+lam] = a21;
        ctxp[wv][3*Dd + lam] = a30; ctxp[wv][3*Dd + 64+lam] = a31;
    }
    __syncthreads();
    for (int q = tid; q < 512; q += 256) {
        float s = ctxp[0][q] + ctxp[1][q] + ctxp[2][q] + ctxp[3][q];
        tau[q>>7][Dd + (q&127)] = s;
    }
    __syncthreads();

    // ---- Phase N-B: neighbor pair logits; thread = (j, c) ----
    {
        int j = tid >> 3, c = tid & 7;
        float b2c = nr_b2[0];
        float rpx[4], rpy[4], rvx[4], rvy[4], dd[4], am[4], ad[4];
        #pragma unroll
        for (int r = 0; r < 4; ++r) {
            float pxi = astate[(r0+r)*5+0], pyi = astate[(r0+r)*5+1];
            float vxi = astate[(r0+r)*5+3], vyi = astate[(r0+r)*5+4];
            rpx[r] = jd[r][j][0] - pxi; rpy[r] = jd[r][j][1] - pyi;
            rvx[r] = jd[r][j][2] - vxi; rvy[r] = jd[r][j][3] - vyi;
            dd[r]  = sqrtf(rpx[r]*rpx[r] + rpy[r]*rpy[r]);
            am[r] = 0.f; ad[r] = 0.f;
        }
        #pragma unroll
        for (int u = 0; u < 16; ++u) {
            int hh = (u<<3) + c;
            float wA = w1n_s[hh], wB = w1n_s[Hh+hh], wC = w1n_s[2*Hh+hh];
            float wD = w1n_s[3*Hh+hh], wE = w1n_s[4*Hh+hh];
            float bb = b1n_s[hh], w2 = w2n_s[hh];
            #pragma unroll
            for (int r = 0; r < 4; ++r) {
                float t1 = fmaf(rpx[r], wA, fmaf(rpy[r], wB, fmaf(rvx[r], wC,
                           fmaf(rvy[r], wD, fmaf(dd[r], wE, bb)))));
                t1 = fmaxf(t1, 0.f);
                am[r] = fmaf(t1, w2, am[r]);
                float ejv = a_emb[((size_t)((b*Nn + j)*Tt + t0 + r))*Dd + hh];
                ad[r] = fmaf(tau[r][hh], ejv, ad[r]);
            }
        }
        #pragma unroll
        for (int r = 0; r < 4; ++r) {
            am[r] += __shfl_xor(am[r], 1); ad[r] += __shfl_xor(ad[r], 1);
            am[r] += __shfl_xor(am[r], 2); ad[r] += __shfl_xor(ad[r], 2);
            am[r] += __shfl_xor(am[r], 4); ad[r] += __shfl_xor(ad[r], 4);
        }
        if (c == 0) {
            #pragma unroll
            for (int r = 0; r < 4; ++r) {
                bool vi = amask[r0+r] > 0.5f;
                bool vj = jd[r][j][4] > 0.5f;
                bool ok = vi && vj && (dd[r] <= 30.0f) && (j != i);
                lgn[r][j] = ok ? fmaf(ad[r], RSQRT_D, b2c + am[r]) : -1e30f;
            }
        }
    }
    __syncthreads();

    // ---- Phase N-C: softmax over 32 j, wave per row ----
    {
        float x = (lam < Nn) ? lgn[wv][lam] : -1e30f;
        float mxv = x;
        for (int off = 32; off; off >>= 1) mxv = fmaxf(mxv, __shfl_xor(mxv, off));
        float e = (x > -1e29f) ? expf(x - mxv) : 0.f;
        float sm = e;
        for (int off = 32; off; off >>= 1) sm += __shfl_xor(sm, off);
        float inv = 1.f / fmaxf(sm, 1e-9f);
        if (lam < Nn) p4n[lam][wv] = e * inv;
    }
    __syncthreads();

    // ---- Phase N-D: nbr ctx; threads (d:128, half:2), j-range 16 each ----
    {
        int d = tid & 127, hf = tid >> 7;
        float ac[4] = {0.f,0.f,0.f,0.f};
        #pragma unroll
        for (int jj = 0; jj < 16; ++jj) {
            int j2 = (hf<<4) + jj;
            float4 pv = *(const float4*)&p4n[j2][0];
            size_t base = (size_t)((b*Nn + j2)*Tt + t0);
            float v0 = a_emb[(base+0)*Dd + d];
            float v1 = a_emb[(base+1)*Dd + d];
            float v2 = a_emb[(base+2)*Dd + d];
            float v3 = a_emb[(base+3)*Dd + d];
            ac[0] = fmaf(pv.x, v0, ac[0]);
            ac[1] = fmaf(pv.y, v1, ac[1]);
            ac[2] = fmaf(pv.z, v2, ac[2]);
            ac[3] = fmaf(pv.w, v3, ac[3]);
        }
        if (hf == 1) {
            #pragma unroll
            for (int r = 0; r < 4; ++r) ctxp[0][r*Dd + d] = ac[r];
        }
        __syncthreads();
        if (hf == 0) {
            #pragma unroll
            for (int r = 0; r < 4; ++r) tau[r][2*Dd + d] = ac[r] + ctxp[0][r*Dd + d];
        }
    }
    __syncthreads();

    // ---- Phase N-E: to layer1 (384->128); thread (h, rp) does rows rp, rp+2 ----
    {
        int h = tid & 127, rp = tid >> 7;
        float ta[6], tb[6];
        #pragma unroll
        for (int c = 0; c < 6; ++c) {
            ta[c] = tau[rp][c*64 + lam];
            tb[c] = tau[rp+2][c*64 + lam];
        }
        float acc0 = 0.f, acc1 = 0.f;
        #pragma unroll
        for (int c = 0; c < 6; ++c) {
            #pragma unroll
            for (int kk = 0; kk < 64; ++kk) {
                float w = to_w1[(c*64+kk)*Hh + h];
                acc0 = fmaf(rlane(ta[c], kk), w, acc0);
                acc1 = fmaf(rlane(tb[c], kk), w, acc1);
            }
        }
        float bv = to_b1[h];
        g1s[rp][h]   = fmaxf(acc0 + bv, 0.f);
        g1s[rp+2][h] = fmaxf(acc1 + bv, 0.f);
    }
    __syncthreads();

    // ---- Phase N-F: to layer2 (128->64); wave wv = row wv, lane = o ----
    {
        float ga = g1s[wv][lam], gb = g1s[wv][64+lam];
        float acc = to_b2[lam];
        #pragma unroll
        for (int kk = 0; kk < 64; ++kk)
            acc = fmaf(rlane(ga, kk), to_w2[kk*TAUu + lam], acc);
        #pragma unroll
        for (int kk = 0; kk < 64; ++kk)
            acc = fmaf(rlane(gb, kk), to_w2[(64+kk)*TAUu + lam], acc);
        float mk = (amask[r0+wv] > 0.5f) ? 1.f : 0.f;
        out[(r0+wv)*TAUu + lam] = acc * mk;
    }
}

extern "C" void kernel_launch(void* const* d_in, const int* in_sizes, int n_in,
                              void* d_out, int out_size, void* d_ws, size_t ws_size,
                              hipStream_t stream) {
    const float* agents_state  = (const float*)d_in[0];
    const float* agents_mask   = (const float*)d_in[1];
    const float* map_polylines = (const float*)d_in[2];
    const float* map_poly_mask = (const float*)d_in[3];
    const int*   map_poly_type = (const int*)d_in[4];
    const int*   map_tl_status = (const int*)d_in[5];
    const int*   map_on_route  = (const int*)d_in[6];
    const float* pm_w1 = (const float*)d_in[7];
    const float* pm_b1 = (const float*)d_in[8];
    const float* pm_w2 = (const float*)d_in[9];
    const float* pm_b2 = (const float*)d_in[10];
    const float* type_emb  = (const float*)d_in[11];
    const float* tl_emb    = (const float*)d_in[12];
    const float* route_emb = (const float*)d_in[13];
    const float* mo_w1 = (const float*)d_in[14];
    const float* mo_b1 = (const float*)d_in[15];
    const float* mo_w2 = (const float*)d_in[16];
    const float* mo_b2 = (const float*)d_in[17];
    const float* ae_w1 = (const float*)d_in[18];
    const float* ae_b1 = (const float*)d_in[19];
    const float* ae_w2 = (const float*)d_in[20];
    const float* ae_b2 = (const float*)d_in[21];
    const float* ae_w3 = (const float*)d_in[22];
    const float* ae_b3 = (const float*)d_in[23];
    const float* mr_w1 = (const float*)d_in[24];
    const float* mr_b1 = (const float*)d_in[25];
    const float* mr_w2 = (const float*)d_in[26];
    const float* mr_b2 = (const float*)d_in[27];
    const float* nr_w1 = (const float*)d_in[28];
    const float* nr_b1 = (const float*)d_in[29];
    const float* nr_w2 = (const float*)d_in[30];
    const float* nr_b2 = (const float*)d_in[31];
    const float* to_w1 = (const float*)d_in[32];
    const float* to_b1 = (const float*)d_in[33];
    const float* to_w2 = (const float*)d_in[34];
    const float* to_b2 = (const float*)d_in[35];

    float* ws = (float*)d_ws;
    float* map_node   = ws;                 // B*M*D   = 65536
    float* map_nodeT  = ws + 65536;         // B*D*M   = 65536
    float* map_center = ws + 131072;        // B*M*2   = 1024
    float* a_emb      = ws + 132096;        // B*N*T*D = 262144

    float* out = (float*)d_out;

    k_map<<<Bb*Mm, 128, 0, stream>>>(map_polylines, map_poly_mask,
        map_poly_type, map_tl_status, map_on_route,
        pm_w1, pm_b1, pm_w2, pm_b2, type_emb, tl_emb, route_emb,
        mo_w1, mo_b1, mo_w2, mo_b2, map_node, map_nodeT, map_center);

    k_agent<<<Bb*Nn*Tt/4, 128, 0, stream>>>(agents_state, agents_mask,
        ae_w1, ae_b1, ae_w2, ae_b2, ae_w3, ae_b3, a_emb);

    k_fused<<<Bb*Nn*Tt/4, 256, 0, stream>>>(agents_state, agents_mask,
        map_poly_mask, a_emb, map_node, map_nodeT, map_center,
        mr_w1, mr_b1, mr_w2, mr_b2,
        nr_w1, nr_b1, nr_w2, nr_b2,
        to_w1, to_b1, to_w2, to_b2, out);
}